// Round 8
// baseline (144.079 us; speedup 1.0000x reference)
//
#include <hip/hip_runtime.h>
#include <math.h>

// AFM: B=4096, F=50, D=16, A=32, P=1225 pairs.
// out[b] = sum_p softmax_p( relu(inter_p @ W) . h ) * (inter_p . p_vec)
//
// Round 8: DIAGNOSTIC + optimization. Grid 128 blocks x 32 batches/block
// (half the CUs, 2x work per active CU) -> kernel duration ~2x -> visible in
// rocprof top-5 above the harness's 41us fills, recovering counters after 4
// blind rounds. Embedded opts: 4 independent batch-chains per wave (shared
// table decode, ILP x4), prologue amortized over 32 batches, no VGPR cap.
//  - 32-pair tiles on mfma_f32_32x32x16_f16 (K=16). Layouts validated R4-R7:
//    A[m=lane&31][k=(lane>>5)*8+jj], B[k][n=lane&31],
//    C/D row a=(reg&3)+8*(reg>>2)+4*(lane>>5), col n=lane&31.
//  - No-max softmax in log2 domain (scores bounded; R7 absmax 0.125 passed).
//  - Table: interleaved uint2 {ent(2t,n), ent(2t+1,n)}, ent=(i*48)<<16|(j*48).

#define FF 50
#define DD 16
#define AA 32
#define NP 1225
#define NT 39              // tiles of 32 pairs; tile 38 partial (9 valid)
#define NTP 40
#define ERS 24             // halves per e-row (48 B)
#define EBS (FF * ERS)     // 1200 halves per batch element
#define BPB 32             // batches per block

typedef _Float16 half8 __attribute__((ext_vector_type(8)));
typedef _Float16 half4 __attribute__((ext_vector_type(4)));
typedef _Float16 half2v __attribute__((ext_vector_type(2)));
typedef float    floatx16 __attribute__((ext_vector_type(16)));

__global__ __launch_bounds__(256) void afm_kernel(
    const float* __restrict__ feat,   // [B, 50, 16]
    const float* __restrict__ W,      // [16, 32]
    const float* __restrict__ h,      // [32]
    const float* __restrict__ pvec,   // [16]
    float* __restrict__ out,          // [B]
    int Btot)
{
  __shared__ __align__(16) _Float16 eh[BPB * EBS];  // 76800 B
  __shared__ unsigned int tbl[NTP * 32];            // 5120 B

  const int tid    = threadIdx.x;
  const int lane   = tid & 63;
  const int wave   = tid >> 6;
  const int halfid = lane >> 5;
  const int n      = lane & 31;
  const int b0     = blockIdx.x * BPB;

  // ---- stage 32 batch elements -> f16 LDS ----
  for (int s = tid; s < BPB * 200; s += 256) {
    int bl  = s / 200;
    int rem = s - bl * 200;
    int bb  = b0 + bl;
    if (bb < Btot) {
      float4 v4 = ((const float4*)feat)[(size_t)bb * 200 + rem];
      half4 hv;
      hv[0] = (_Float16)v4.x; hv[1] = (_Float16)v4.y;
      hv[2] = (_Float16)v4.z; hv[3] = (_Float16)v4.w;
      int row = rem >> 2, q = rem & 3;
      *(half4*)(&eh[bl * EBS + row * ERS + q * 4]) = hv;
    }
  }

  // ---- interleaved pair table ----
  for (int q = tid; q < NTP * 32; q += 256) {
    int t = ((q >> 6) << 1) | (q & 1);
    int nn = (q >> 1) & 31;
    int p = t * 32 + nn;
    unsigned ent = 0;
    if (p < NP) {
      int rad = 9801 - 8 * p;
      int i = (int)((99.0f - sqrtf((float)rad)) * 0.5f);
      if (i < 0) i = 0; if (i > 48) i = 48;
      int off = (i * (99 - i)) >> 1;
      if (off > p) { --i; off = (i * (99 - i)) >> 1; }
      else {
        int off1 = ((i + 1) * (98 - i)) >> 1;
        if (off1 <= p) { ++i; off = off1; }
      }
      int j = p - off + i + 1;
      ent = ((unsigned)(i * 48) << 16) | (unsigned)(j * 48);
    }
    tbl[q] = ent;
  }

  // ---- loop-invariant fragments ----
  const float LOG2E = 1.4426950408889634f;
  half8 A0;
  #pragma unroll
  for (int jj = 0; jj < 8; ++jj)
    A0[jj] = (_Float16)W[(halfid * 8 + jj) * AA + n];
  float hreg[16];
  #pragma unroll
  for (int r = 0; r < 16; ++r)
    hreg[r] = h[(r & 3) + 8 * (r >> 2) + 4 * halfid] * LOG2E;
  half8 PV;
  #pragma unroll
  for (int k = 0; k < 8; ++k) PV[k] = (_Float16)pvec[halfid * 8 + k];
  const floatx16 ZACC = (floatx16)0.0f;

  __syncthreads();

  // per-tile core for one batch, given LDS byte offsets oi, oj
  auto core = [&](const char* eb, unsigned oi, unsigned oj,
                  float& vout, float& gout) {
    half8 Bi = *(const half8*)(eb + oi);
    half8 Bj = *(const half8*)(eb + oj);
    half8 Bv = Bi * Bj;
    floatx16 z = __builtin_amdgcn_mfma_f32_32x32x16_f16(A0, Bv, ZACC, 0, 0, 0);
    float a0 = 0.f, a1 = 0.f, a2 = 0.f, a3 = 0.f;
    #pragma unroll
    for (int r = 0; r < 16; r += 4) {
      a0 = fmaf(fmaxf(z[r + 0], 0.f), hreg[r + 0], a0);
      a1 = fmaf(fmaxf(z[r + 1], 0.f), hreg[r + 1], a1);
      a2 = fmaf(fmaxf(z[r + 2], 0.f), hreg[r + 2], a2);
      a3 = fmaf(fmaxf(z[r + 3], 0.f), hreg[r + 3], a3);
    }
    float v = (a0 + a1) + (a2 + a3);
    vout = v + __shfl_xor(v, 32, 64);         // combine K-halves (log2 domain)
    half8 gp = Bv * PV;                       // g partial (this K-half)
    half4 g4 = {(_Float16)(gp[0] + gp[4]), (_Float16)(gp[1] + gp[5]),
                (_Float16)(gp[2] + gp[6]), (_Float16)(gp[3] + gp[7])};
    half2v g2 = {(_Float16)(g4[0] + g4[2]), (_Float16)(g4[1] + g4[3])};
    gout = (float)g2[0] + (float)g2[1];
  };

  const unsigned int* tpair = tbl + 2 * n;

  // ---- this wave owns 8 batches: 2 groups of 4 independent chains ----
  for (int grp = 0; grp < 2; ++grp) {
    const int bg = b0 + wave * 8 + grp * 4;   // first batch of this group
    const char* eb0 = (const char*)(eh + (wave * 8 + grp * 4) * EBS)
                      + halfid * 16;
    float den[4] = {0.f, 0.f, 0.f, 0.f};
    float num[4] = {0.f, 0.f, 0.f, 0.f};

    for (int th = 0; th < 19; ++th) {         // tiles 0..37, all valid
      uint2 ij2 = *(const uint2*)(tpair + th * 64);
      unsigned oi0 = ij2.x >> 16, oj0 = ij2.x & 0xffffu;
      unsigned oi1 = ij2.y >> 16, oj1 = ij2.y & 0xffffu;
      #pragma unroll
      for (int q = 0; q < 4; ++q) {
        float v, g;
        core(eb0 + q * (EBS * 2), oi0, oj0, v, g);
        float e = exp2f(v);
        den[q] += e; num[q] = fmaf(e, g, num[q]);
      }
      #pragma unroll
      for (int q = 0; q < 4; ++q) {
        float v, g;
        core(eb0 + q * (EBS * 2), oi1, oj1, v, g);
        float e = exp2f(v);
        den[q] += e; num[q] = fmaf(e, g, num[q]);
      }
    }
    {                                         // peeled tile 38: valid n < 9
      unsigned ij = tpair[19 * 64];
      unsigned oi = ij >> 16, oj = ij & 0xffffu;
      #pragma unroll
      for (int q = 0; q < 4; ++q) {
        float v, g;
        core(eb0 + q * (EBS * 2), oi, oj, v, g);
        if (n >= 9) v = -3.0e38f;
        float e = exp2f(v);
        den[q] += e; num[q] = fmaf(e, g, num[q]);
      }
    }

    // butterfly: pure adds (mask-32 merges g-halves; den double-counts)
    #pragma unroll
    for (int mask = 32; mask >= 1; mask >>= 1) {
      #pragma unroll
      for (int q = 0; q < 4; ++q) {
        den[q] += __shfl_xor(den[q], mask, 64);
        num[q] += __shfl_xor(num[q], mask, 64);
      }
    }
    if (lane == 0) {
      #pragma unroll
      for (int q = 0; q < 4; ++q)
        if (bg + q < Btot) out[bg + q] = (2.0f * num[q]) / den[q];
    }
  }
}

extern "C" void kernel_launch(void* const* d_in, const int* in_sizes, int n_in,
                              void* d_out, int out_size, void* d_ws, size_t ws_size,
                              hipStream_t stream) {
  const float* feat = (const float*)d_in[0];
  const float* W    = (const float*)d_in[1];
  const float* h    = (const float*)d_in[2];
  const float* pvec = (const float*)d_in[3];
  float* out = (float*)d_out;
  const int B = in_sizes[0] / (FF * DD);   // 4096
  afm_kernel<<<(B + BPB - 1) / BPB, 256, 0, stream>>>(feat, W, h, pvec, out, B);
}

// Round 9
// 87.267 us; speedup vs baseline: 1.6510x; 1.6510x over previous
//
#include <hip/hip_runtime.h>
#include <math.h>

// AFM: B=4096, F=50, D=16, A=32, P=1225 pairs.
// out[b] = sum_p softmax_p( relu(inter_p @ W) . h ) * (inter_p . p_vec)
//
// Round 9: occupancy + instruction diet, driven by R8 counters
// (per-active-CU VALU duty ~49% at 0.9 waves/SIMD => latency half, fat half).
//  - 256 blocks x 512 threads, BPB=16: 16 waves/CU = 4 waves/SIMD
//    (__launch_bounds__(512,4) caps VGPR<=128; R8 measured 88).
//  - 2 independent batch-chains per wave; table decode shared.
//  - g-reduction: 4x v_dot2_f32_f16 (was ~20-inst f16 extract/add tree).
//  - 32-pair tiles on mfma_f32_32x32x16_f16 (K=16). Layouts validated R4-R8:
//    A[m=lane&31][k=(lane>>5)*8+jj], B[k][n=lane&31],
//    C/D row a=(reg&3)+8*(reg>>2)+4*(lane>>5), col n=lane&31.
//  - No-max softmax in log2 domain (validated R7/R8, absmax 0.125).

#define FF 50
#define DD 16
#define AA 32
#define NP 1225
#define NT 39              // tiles of 32 pairs; tile 38 partial (9 valid)
#define NTP 40
#define ERS 24             // halves per e-row (48 B)
#define EBS (FF * ERS)     // 1200 halves per batch element
#define BPB 16             // batches per block
#define NTHR 512

typedef _Float16 half8 __attribute__((ext_vector_type(8)));
typedef _Float16 half4 __attribute__((ext_vector_type(4)));
typedef _Float16 half2v __attribute__((ext_vector_type(2)));
typedef __fp16   fh2    __attribute__((ext_vector_type(2)));
typedef float    floatx16 __attribute__((ext_vector_type(16)));

__global__ __launch_bounds__(NTHR, 4) void afm_kernel(
    const float* __restrict__ feat,   // [B, 50, 16]
    const float* __restrict__ W,      // [16, 32]
    const float* __restrict__ h,      // [32]
    const float* __restrict__ pvec,   // [16]
    float* __restrict__ out,          // [B]
    int Btot)
{
  __shared__ __align__(16) _Float16 eh[BPB * EBS];  // 38400 B
  __shared__ unsigned int tbl[NTP * 32];            // 5120 B

  const int tid    = threadIdx.x;
  const int lane   = tid & 63;
  const int wave   = tid >> 6;       // 0..7
  const int halfid = lane >> 5;
  const int n      = lane & 31;
  const int b0     = blockIdx.x * BPB;

  // ---- stage 16 batch elements -> f16 LDS ----
  for (int s = tid; s < BPB * 200; s += NTHR) {
    int bl  = s / 200;
    int rem = s - bl * 200;
    int bb  = b0 + bl;
    if (bb < Btot) {
      float4 v4 = ((const float4*)feat)[(size_t)bb * 200 + rem];
      half4 hv;
      hv[0] = (_Float16)v4.x; hv[1] = (_Float16)v4.y;
      hv[2] = (_Float16)v4.z; hv[3] = (_Float16)v4.w;
      int row = rem >> 2, q = rem & 3;
      *(half4*)(&eh[bl * EBS + row * ERS + q * 4]) = hv;
    }
  }

  // ---- interleaved pair table: dword q holds ent(t,nn),
  //      t=2*(q>>6)+(q&1), nn=(q>>1)&31; ent=(i*48)<<16|(j*48) ----
  for (int q = tid; q < NTP * 32; q += NTHR) {
    int t = ((q >> 6) << 1) | (q & 1);
    int nn = (q >> 1) & 31;
    int p = t * 32 + nn;
    unsigned ent = 0;
    if (p < NP) {
      int rad = 9801 - 8 * p;
      int i = (int)((99.0f - sqrtf((float)rad)) * 0.5f);
      if (i < 0) i = 0; if (i > 48) i = 48;
      int off = (i * (99 - i)) >> 1;
      if (off > p) { --i; off = (i * (99 - i)) >> 1; }
      else {
        int off1 = ((i + 1) * (98 - i)) >> 1;
        if (off1 <= p) { ++i; off = off1; }
      }
      int j = p - off + i + 1;
      ent = ((unsigned)(i * 48) << 16) | (unsigned)(j * 48);
    }
    tbl[q] = ent;
  }

  // ---- loop-invariant fragments ----
  const float LOG2E = 1.4426950408889634f;
  half8 A0;
  #pragma unroll
  for (int jj = 0; jj < 8; ++jj)
    A0[jj] = (_Float16)W[(halfid * 8 + jj) * AA + n];
  float hreg[16];
  #pragma unroll
  for (int r = 0; r < 16; ++r)
    hreg[r] = h[(r & 3) + 8 * (r >> 2) + 4 * halfid] * LOG2E;
  fh2 pv2[4];                         // pvec slice (f16) for this K-half
  #pragma unroll
  for (int q = 0; q < 4; ++q) {
    pv2[q][0] = (__fp16)pvec[halfid * 8 + 2 * q];
    pv2[q][1] = (__fp16)pvec[halfid * 8 + 2 * q + 1];
  }
  const floatx16 ZACC = (floatx16)0.0f;

  __syncthreads();

  // per-tile core for one batch, given LDS byte offsets oi, oj
  auto core = [&](const char* eb, unsigned oi, unsigned oj,
                  float& vout, float& gout) {
    half8 Bi = *(const half8*)(eb + oi);
    half8 Bj = *(const half8*)(eb + oj);
    half8 Bv = Bi * Bj;                       // 4x v_pk_mul_f16
    floatx16 z = __builtin_amdgcn_mfma_f32_32x32x16_f16(A0, Bv, ZACC, 0, 0, 0);
    float a0 = 0.f, a1 = 0.f, a2 = 0.f, a3 = 0.f;
    #pragma unroll
    for (int r = 0; r < 16; r += 4) {
      a0 = fmaf(fmaxf(z[r + 0], 0.f), hreg[r + 0], a0);
      a1 = fmaf(fmaxf(z[r + 1], 0.f), hreg[r + 1], a1);
      a2 = fmaf(fmaxf(z[r + 2], 0.f), hreg[r + 2], a2);
      a3 = fmaf(fmaxf(z[r + 3], 0.f), hreg[r + 3], a3);
    }
    float v = (a0 + a1) + (a2 + a3);
    vout = v + __shfl_xor(v, 32, 64);         // combine K-halves (log2 domain)
    // g partial (this K-half): 4x v_dot2_f32_f16, register-renamed casts
#if __has_builtin(__builtin_amdgcn_fdot2)
    fh2 q0 = __builtin_bit_cast(fh2, (half2v)__builtin_shufflevector(Bv, Bv, 0, 1));
    fh2 q1 = __builtin_bit_cast(fh2, (half2v)__builtin_shufflevector(Bv, Bv, 2, 3));
    fh2 q2 = __builtin_bit_cast(fh2, (half2v)__builtin_shufflevector(Bv, Bv, 4, 5));
    fh2 q3 = __builtin_bit_cast(fh2, (half2v)__builtin_shufflevector(Bv, Bv, 6, 7));
    float gp0 = __builtin_amdgcn_fdot2(q1, pv2[1],
                __builtin_amdgcn_fdot2(q0, pv2[0], 0.f, false), false);
    float gp1 = __builtin_amdgcn_fdot2(q3, pv2[3],
                __builtin_amdgcn_fdot2(q2, pv2[2], 0.f, false), false);
    gout = gp0 + gp1;
#else
    float gp = 0.f;
    #pragma unroll
    for (int k = 0; k < 8; ++k)
      gp = fmaf((float)Bv[k], (float)((const __fp16*)&pv2[0])[k], gp);
    gout = gp;
#endif
  };

  // ---- this wave owns batches bA = b0 + 2*wave, bB = bA + 1 ----
  const char* ebA = (const char*)(eh + (2 * wave) * EBS) + halfid * 16;
  const char* ebB = ebA + EBS * sizeof(_Float16);

  float denA = 0.f, numA = 0.f, denB = 0.f, numB = 0.f;
  const unsigned int* tpair = tbl + 2 * n;

  for (int th = 0; th < 19; ++th) {           // tiles 0..37, all valid
    uint2 ij2 = *(const uint2*)(tpair + th * 64);
    unsigned oi0 = ij2.x >> 16, oj0 = ij2.x & 0xffffu;
    unsigned oi1 = ij2.y >> 16, oj1 = ij2.y & 0xffffu;
    float v, g;
    core(ebA, oi0, oj0, v, g);
    { float e = exp2f(v); denA += e; numA = fmaf(e, g, numA); }
    core(ebB, oi0, oj0, v, g);
    { float e = exp2f(v); denB += e; numB = fmaf(e, g, numB); }
    core(ebA, oi1, oj1, v, g);
    { float e = exp2f(v); denA += e; numA = fmaf(e, g, numA); }
    core(ebB, oi1, oj1, v, g);
    { float e = exp2f(v); denB += e; numB = fmaf(e, g, numB); }
  }
  {                                           // peeled tile 38: valid n < 9
    unsigned ij = tpair[19 * 64];
    unsigned oi = ij >> 16, oj = ij & 0xffffu;
    float v, g;
    core(ebA, oi, oj, v, g);
    if (n >= 9) v = -3.0e38f;
    { float e = exp2f(v); denA += e; numA = fmaf(e, g, numA); }
    core(ebB, oi, oj, v, g);
    if (n >= 9) v = -3.0e38f;
    { float e = exp2f(v); denB += e; numB = fmaf(e, g, numB); }
  }

  // ---- butterfly: pure adds (mask-32 merges g-halves; den double-counts) ----
  #pragma unroll
  for (int mask = 32; mask >= 1; mask >>= 1) {
    denA += __shfl_xor(denA, mask, 64);
    numA += __shfl_xor(numA, mask, 64);
    denB += __shfl_xor(denB, mask, 64);
    numB += __shfl_xor(numB, mask, 64);
  }
  const int bA = b0 + 2 * wave;
  if (lane == 0 && bA < Btot)     out[bA]     = (2.0f * numA) / denA;
  if (lane == 0 && bA + 1 < Btot) out[bA + 1] = (2.0f * numB) / denB;
}

extern "C" void kernel_launch(void* const* d_in, const int* in_sizes, int n_in,
                              void* d_out, int out_size, void* d_ws, size_t ws_size,
                              hipStream_t stream) {
  const float* feat = (const float*)d_in[0];
  const float* W    = (const float*)d_in[1];
  const float* h    = (const float*)d_in[2];
  const float* pvec = (const float*)d_in[3];
  float* out = (float*)d_out;
  const int B = in_sizes[0] / (FF * DD);   // 4096
  afm_kernel<<<(B + BPB - 1) / BPB, NTHR, 0, stream>>>(feat, W, h, pvec, out, B);
}